// Round 3
// baseline (761.433 us; speedup 1.0000x reference)
//
#include <hip/hip_runtime.h>

#define BN_EPS 1e-5f

// ================================================================ adder2d
// One thread = one spatial position (b,ho,wo), CT output channels in registers.
// Per ci: load K*K patch once, reuse across CT channels. Weight addresses are
// wave-uniform -> scalar loads. Optional fused input transform relu((x-m)*r)
// applied to IN-BOUNDS loads only (zero padding stays 0, matching patch
// extraction applied AFTER the activation).
// Emits per-wave (sum, sumsq) BN partials for each of its CT channels.
// REQUIRES B*Ho*Wo % 64 == 0 (true for all shapes here).
template<int K, int CT, bool INBN>
__global__ void __launch_bounds__(64)
adder_bn2(const float* __restrict__ x, const float* __restrict__ instats,
          const float* __restrict__ w, float* __restrict__ raw,
          float2* __restrict__ partials,
          int B, int Cin, int Cout, int H, int W, int Ho, int Wo,
          int stride, int pad, int nChunks) {
  const int chunk = blockIdx.x;
  const int co0 = blockIdx.y * CT;
  const int HWo = Ho * Wo;
  const int i = chunk * 64 + threadIdx.x;
  const int b = i / HWo;
  const int hw = i - b * HWo;
  const int ho = hw / Wo, wo = hw - ho * Wo;
  const int KK = K * K;

  float acc[CT];
  #pragma unroll
  for (int c = 0; c < CT; c++) acc[c] = 0.f;

  for (int ci = 0; ci < Cin; ci++) {
    float mS = 0.f, rS = 0.f;
    if (INBN) { mS = instats[ci]; rS = instats[Cin + ci]; }   // uniform -> sgpr
    const float* xp = x + (b * Cin + ci) * H * W;
    float p[K * K];
    #pragma unroll
    for (int kh = 0; kh < K; kh++) {
      int hh = ho * stride + kh - pad;
      bool hv = (hh >= 0) & (hh < H);
      #pragma unroll
      for (int kw = 0; kw < K; kw++) {
        int ww = wo * stride + kw - pad;
        bool ok = hv & (ww >= 0) & (ww < W);
        float v = ok ? xp[hh * W + ww] : 0.f;
        if (INBN) v = ok ? fmaxf((v - mS) * rS, 0.f) : 0.f;
        p[kh * K + kw] = v;
      }
    }
    const float* wp = w + (co0 * Cin + ci) * KK;   // uniform -> s_load
    #pragma unroll
    for (int c = 0; c < CT; c++) {
      #pragma unroll
      for (int t = 0; t < KK; t++)
        acc[c] += fabsf(p[t] - wp[c * Cin * KK + t]);
    }
  }

  #pragma unroll
  for (int c = 0; c < CT; c++) {
    float v = -acc[c];
    raw[(b * Cout + co0 + c) * HWo + hw] = v;
    float sx = v, sy = v * v;
    #pragma unroll
    for (int off = 32; off; off >>= 1) {
      sx += __shfl_down(sx, off, 64);
      sy += __shfl_down(sy, off, 64);
    }
    if (threadIdx.x == 0) partials[(co0 + c) * nChunks + chunk] = make_float2(sx, sy);
  }
}

// ================================================================ conv stem + BN partials
// x [32,3,32,32], w [16,3,3,3], raw [32,16,32,32]. grid (128, 16), block 256.
__global__ void __launch_bounds__(256)
conv_stem_bn(const float* __restrict__ x, const float* __restrict__ w,
             float* __restrict__ raw, float2* __restrict__ partials) {
  const int co = blockIdx.y;
  const int i = blockIdx.x * 256 + threadIdx.x;   // over B*1024
  const int b = i >> 10, hw = i & 1023;
  const int ho = hw >> 5, wo = hw & 31;
  float acc = 0.f;
  #pragma unroll
  for (int ci = 0; ci < 3; ci++) {
    const float* xp = x + (b * 3 + ci) * 1024;
    #pragma unroll
    for (int kh = 0; kh < 3; kh++) {
      int hh = ho + kh - 1;
      bool hv = (hh >= 0) & (hh < 32);
      #pragma unroll
      for (int kw = 0; kw < 3; kw++) {
        int ww = wo + kw - 1;
        float xv = (hv & (ww >= 0) & (ww < 32)) ? xp[hh * 32 + ww] : 0.f;
        acc += xv * w[((co * 3 + ci) * 3 + kh) * 3 + kw];
      }
    }
  }
  raw[(b * 16 + co) * 1024 + hw] = acc;

  float sx = acc, sy = acc * acc;
  #pragma unroll
  for (int off = 32; off; off >>= 1) {
    sx += __shfl_down(sx, off, 64);
    sy += __shfl_down(sy, off, 64);
  }
  __shared__ float2 red[4];
  int lane = threadIdx.x & 63, wid = threadIdx.x >> 6;
  if (lane == 0) red[wid] = make_float2(sx, sy);
  __syncthreads();
  if (threadIdx.x == 0) {
    float2 t = red[0];
    t.x += red[1].x + red[2].x + red[3].x;
    t.y += red[1].y + red[2].y + red[3].y;
    partials[co * 128 + blockIdx.x] = t;
  }
}

// ================================================================ BN finalize
// grid = C blocks, 64 threads. stats: [mean[C], rstd[C]]
__global__ void bn_finalize(const float2* __restrict__ partials, float* __restrict__ stats,
                            int C, int S, float invN) {
  int c = blockIdx.x;
  float s = 0.f, s2 = 0.f;
  for (int j = threadIdx.x; j < S; j += 64) {
    float2 p = partials[c * S + j];
    s += p.x; s2 += p.y;
  }
  #pragma unroll
  for (int off = 32; off; off >>= 1) {
    s  += __shfl_down(s, off, 64);
    s2 += __shfl_down(s2, off, 64);
  }
  if (threadIdx.x == 0) {
    float m = s * invN;
    float var = fmaxf(s2 * invN - m * m, 0.f);
    stats[c]     = m;
    stats[C + c] = rsqrtf(var + BN_EPS);
  }
}

// ================================================================ combine
// h = relu( (raw2 - m2)*r2 + identity )
// IDMODE 0: identity = idsrc                      (materialized h)
// IDMODE 1: identity = (idsrc - mI)*rI            (downsample BN)
// IDMODE 2: identity = relu((idsrc - mI)*rI)      (stem output)
template<int IDMODE>
__global__ void __launch_bounds__(256)
combine_k(const float* __restrict__ raw2, const float* __restrict__ stats2,
          const float* __restrict__ idsrc, const float* __restrict__ statsI,
          float* __restrict__ h, int C, int HW) {
  int idx = blockIdx.x * 256 + threadIdx.x;
  int c = (idx / HW) % C;
  float y = (raw2[idx] - stats2[c]) * stats2[C + c];
  float id;
  if (IDMODE == 0) id = idsrc[idx];
  else {
    id = (idsrc[idx] - statsI[c]) * statsI[C + c];
    if (IDMODE == 2) id = fmaxf(id, 0.f);
  }
  h[idx] = fmaxf(y + id, 0.f);
}

// ================================================================ head
// h [32,64,8,8] -> global mean -> fc (10,64) -> BN over batch -> out [32,10]
__global__ void head_kernel(const float* __restrict__ h, const float* __restrict__ fcw,
                            float* __restrict__ out) {
  __shared__ float pooled[32 * 64];
  __shared__ float logits[32 * 10];
  __shared__ float mn[10], rs[10];
  int t = threadIdx.x;
  for (int i = t; i < 32 * 64; i += blockDim.x) {
    const float* p = h + i * 64;
    float s = 0.f;
    #pragma unroll
    for (int j = 0; j < 64; j++) s += p[j];
    pooled[i] = s * (1.f / 64.f);
  }
  __syncthreads();
  for (int i = t; i < 320; i += blockDim.x) {
    int b = i / 10, o = i % 10;
    float s = 0.f;
    #pragma unroll
    for (int c = 0; c < 64; c++) s += pooled[b * 64 + c] * fcw[o * 64 + c];
    logits[i] = s;
  }
  __syncthreads();
  if (t < 10) {
    float s = 0.f;
    for (int b = 0; b < 32; b++) s += logits[b * 10 + t];
    float m = s / 32.f;
    float v = 0.f;
    for (int b = 0; b < 32; b++) { float d = logits[b * 10 + t] - m; v += d * d; }
    mn[t] = m;
    rs[t] = rsqrtf(v / 32.f + BN_EPS);
  }
  __syncthreads();
  for (int i = t; i < 320; i += blockDim.x) {
    int o = i % 10;
    out[i] = (logits[i] - mn[o]) * rs[o];
  }
}

// ================================================================ host
static inline void fin(hipStream_t s, float2* part, float* stats, int C, int S, float invN) {
  bn_finalize<<<C, 64, 0, s>>>(part, stats, C, S, invN);
}

template<int K, int CT, bool INBN>
static inline void adder(hipStream_t s, const float* x, const float* instats,
                         const float* w, float* raw, float2* part,
                         int B, int Cin, int Cout, int H, int W, int Ho, int Wo,
                         int stride, int pad) {
  int nChunks = (B * Ho * Wo) / 64;
  dim3 g(nChunks, Cout / CT);
  adder_bn2<K, CT, INBN><<<g, 64, 0, s>>>(x, instats, w, raw, part,
                                          B, Cin, Cout, H, W, Ho, Wo, stride, pad, nChunks);
}

extern "C" void kernel_launch(void* const* d_in, const int* in_sizes, int n_in,
                              void* d_out, int out_size, void* d_ws, size_t ws_size,
                              hipStream_t stream) {
  const float* x      = (const float*)d_in[0];
  const float* conv1w = (const float*)d_in[1];
  const float* l1w    = (const float*)d_in[2];
  const float* l2w0   = (const float*)d_in[3];
  const float* l2ws   = (const float*)d_in[4];
  const float* l2down = (const float*)d_in[5];
  const float* l3w0   = (const float*)d_in[6];
  const float* l3ws   = (const float*)d_in[7];
  const float* l3down = (const float*)d_in[8];
  const float* fcw    = (const float*)d_in[9];
  float* out = (float*)d_out;

  const int BUF = 32 * 16 * 32 * 32;  // 524288 floats = 2 MB, max tensor size
  float* base = (float*)d_ws;
  float* H0 = base + 0 * BUF;   // current h
  float* H1 = base + 1 * BUF;   // next h
  float* R0 = base + 2 * BUF;   // stem raw / raw1
  float* R2 = base + 3 * BUF;   // raw2
  float* RD = base + 4 * BUF;   // downsample raw
  float* st = base + 5 * BUF;
  float* stats0 = st;           // 128 floats each
  float* stats1 = st + 128;
  float* stats2 = st + 256;
  float* statsD = st + 384;
  float2* part1 = (float2*)(st + 512);       // 8192 float2 each
  float2* part2 = part1 + 8192;
  float2* partD = part2 + 8192;

  const int B = 32;

  // ---- stem: conv (+fused BN partials) -> stats0. h0 stays virtual (R0+stats0).
  conv_stem_bn<<<dim3(128, 16), 256, 0, stream>>>(x, conv1w, R0, part1);
  fin(stream, part1, stats0, 16, 128, 1.f / 32768.f);

  float* cur = H0;  // materialized block output
  float* nxt = H1;

  // ======== layer1: 3 blocks, 16ch, 32x32, stride 1, CT=8, grid (512,2)
  {
    const int Cin = 16, Cout = 16, Hs = 32, HWo = 1024, N = B * HWo;
    const float invN = 1.f / (float)N;
    const int cblocks = (B * Cout * HWo) / 256;
    for (int i = 0; i < 3; i++) {
      const float* w1 = l1w + (2 * i) * 16 * 16 * 9;
      const float* w2 = l1w + (2 * i + 1) * 16 * 16 * 9;
      if (i == 0) {
        // input = relu(bn(R0)) fused; identity recomputed in combine (mode 2)
        adder<3, 8, true>(stream, R0, stats0, w1, R2 /*raw1 tmp*/, part1, B, Cin, Cout, Hs, Hs, Hs, Hs, 1, 1);
        fin(stream, part1, stats1, Cout, N / 64, invN);
        adder<3, 8, true>(stream, R2, stats1, w2, RD /*raw2 tmp*/, part2, B, Cout, Cout, Hs, Hs, Hs, Hs, 1, 1);
        fin(stream, part2, stats2, Cout, N / 64, invN);
        combine_k<2><<<cblocks, 256, 0, stream>>>(RD, stats2, R0, stats0, nxt, Cout, HWo);
      } else {
        adder<3, 8, false>(stream, cur, nullptr, w1, R2, part1, B, Cin, Cout, Hs, Hs, Hs, Hs, 1, 1);
        fin(stream, part1, stats1, Cout, N / 64, invN);
        adder<3, 8, true>(stream, R2, stats1, w2, RD, part2, B, Cout, Cout, Hs, Hs, Hs, Hs, 1, 1);
        fin(stream, part2, stats2, Cout, N / 64, invN);
        combine_k<0><<<cblocks, 256, 0, stream>>>(RD, stats2, cur, nullptr, nxt, Cout, HWo);
      }
      float* t = cur; cur = nxt; nxt = t;
    }
  }

  // ======== layer2: 32ch @16x16, CT=4
  {
    const int Cout = 32, Ho = 16, HWo = 256, N = B * HWo;
    const float invN = 1.f / (float)N;
    const int cblocks = (B * Cout * HWo) / 256;
    // block1: stride 2, Cin=16, 1x1 adder downsample
    adder<3, 4, false>(stream, cur, nullptr, l2w0, R0, part1, B, 16, Cout, 32, 32, Ho, Ho, 2, 1);
    fin(stream, part1, stats1, Cout, N / 64, invN);
    adder<3, 4, true>(stream, R0, stats1, l2ws + 0 * 9216, R2, part2, B, Cout, Cout, Ho, Ho, Ho, Ho, 1, 1);
    fin(stream, part2, stats2, Cout, N / 64, invN);
    adder<1, 4, false>(stream, cur, nullptr, l2down, RD, partD, B, 16, Cout, 32, 32, Ho, Ho, 2, 0);
    fin(stream, partD, statsD, Cout, N / 64, invN);
    combine_k<1><<<cblocks, 256, 0, stream>>>(R2, stats2, RD, statsD, nxt, Cout, HWo);
    { float* t = cur; cur = nxt; nxt = t; }
    // blocks 2,3
    for (int i = 0; i < 2; i++) {
      const float* w1 = l2ws + (1 + 2 * i) * 9216;
      const float* w2 = l2ws + (2 + 2 * i) * 9216;
      adder<3, 4, false>(stream, cur, nullptr, w1, R0, part1, B, Cout, Cout, Ho, Ho, Ho, Ho, 1, 1);
      fin(stream, part1, stats1, Cout, N / 64, invN);
      adder<3, 4, true>(stream, R0, stats1, w2, R2, part2, B, Cout, Cout, Ho, Ho, Ho, Ho, 1, 1);
      fin(stream, part2, stats2, Cout, N / 64, invN);
      combine_k<0><<<cblocks, 256, 0, stream>>>(R2, stats2, cur, nullptr, nxt, Cout, HWo);
      float* t = cur; cur = nxt; nxt = t;
    }
  }

  // ======== layer3: 64ch @8x8, CT=2
  {
    const int Cout = 64, Ho = 8, HWo = 64, N = B * HWo;
    const float invN = 1.f / (float)N;
    const int cblocks = (B * Cout * HWo) / 256;
    // block1: stride 2, Cin=32, 1x1 adder downsample
    adder<3, 2, false>(stream, cur, nullptr, l3w0, R0, part1, B, 32, Cout, 16, 16, Ho, Ho, 2, 1);
    fin(stream, part1, stats1, Cout, N / 64, invN);
    adder<3, 2, true>(stream, R0, stats1, l3ws + 0 * 36864, R2, part2, B, Cout, Cout, Ho, Ho, Ho, Ho, 1, 1);
    fin(stream, part2, stats2, Cout, N / 64, invN);
    adder<1, 2, false>(stream, cur, nullptr, l3down, RD, partD, B, 32, Cout, 16, 16, Ho, Ho, 2, 0);
    fin(stream, partD, statsD, Cout, N / 64, invN);
    combine_k<1><<<cblocks, 256, 0, stream>>>(R2, stats2, RD, statsD, nxt, Cout, HWo);
    { float* t = cur; cur = nxt; nxt = t; }
    for (int i = 0; i < 2; i++) {
      const float* w1 = l3ws + (1 + 2 * i) * 36864;
      const float* w2 = l3ws + (2 + 2 * i) * 36864;
      adder<3, 2, false>(stream, cur, nullptr, w1, R0, part1, B, Cout, Cout, Ho, Ho, Ho, Ho, 1, 1);
      fin(stream, part1, stats1, Cout, N / 64, invN);
      adder<3, 2, true>(stream, R0, stats1, w2, R2, part2, B, Cout, Cout, Ho, Ho, Ho, Ho, 1, 1);
      fin(stream, part2, stats2, Cout, N / 64, invN);
      combine_k<0><<<cblocks, 256, 0, stream>>>(R2, stats2, cur, nullptr, nxt, Cout, HWo);
      float* t = cur; cur = nxt; nxt = t;
    }
  }

  // ---- head
  head_kernel<<<1, 512, 0, stream>>>(cur, fcw, out);
}

// Round 4
// 406.303 us; speedup vs baseline: 1.8741x; 1.8741x over previous
//
#include <hip/hip_runtime.h>

#define BN_EPS 1e-5f

// ================================================================ stats prologue
// Reduce per-block partials [C][nPart] -> smr[c] = (mean, rstd) in LDS.
// Fixed-order tree reduction: identical result in every block (deterministic).
template<int C>
__device__ __forceinline__ void stats_prologue(const float2* __restrict__ part,
                                               int nPart, float invN,
                                               float2* smr, float2* pred) {
  const int TPC = 256 / C;                 // threads per channel (4..16)
  int c  = threadIdx.x / TPC;
  int sl = threadIdx.x - c * TPC;
  float s = 0.f, s2 = 0.f;
  for (int j = sl; j < nPart; j += TPC) {
    float2 p = part[c * nPart + j];
    s += p.x; s2 += p.y;
  }
  pred[threadIdx.x] = make_float2(s, s2);
  __syncthreads();
  for (int st = TPC >> 1; st; st >>= 1) {
    if (sl < st) {
      pred[threadIdx.x].x += pred[threadIdx.x + st].x;
      pred[threadIdx.x].y += pred[threadIdx.x + st].y;
    }
    __syncthreads();
  }
  if (sl == 0) {
    float m   = pred[threadIdx.x].x * invN;
    float var = fmaxf(pred[threadIdx.x].y * invN - m * m, 0.f);
    smr[c] = make_float2(m, rsqrtf(var + BN_EPS));
  }
  __syncthreads();
}

// ================================================================ adder2d
// One thread = one output position (b,ho,wo) x CT output channels.
// blockDim 256 (4 waves). grid = (B*Ho*Wo/256, Cout/CT).
// INBN: input tensor is a raw pre-BN tensor; transform relu((v-m)*r) applied to
// in-bounds loads only (zero padding stays 0: activation precedes patching).
// Emits per-block (sum,sumsq) partials at partials[co*gridDim.x + blockIdx.x].
template<int K, int CT, int CIN, bool INBN>
__global__ void __launch_bounds__(256)
adder_k(const float* __restrict__ x, const float2* __restrict__ inpart,
        int nPartIn, float invNIn,
        const float* __restrict__ w,
        float* __restrict__ raw, float2* __restrict__ partials,
        int B, int Cout, int H, int W, int Ho, int Wo, int stride, int pad) {
  __shared__ float2 smr[INBN ? CIN : 1];
  __shared__ float2 pred[256];
  if (INBN) stats_prologue<CIN>(inpart, nPartIn, invNIn, smr, pred);

  const int KK  = K * K;
  const int HWo = Ho * Wo;
  const int i   = blockIdx.x * 256 + threadIdx.x;
  const int b   = i / HWo;
  const int hw  = i - b * HWo;
  const int ho  = hw / Wo, wo = hw - ho * Wo;
  const int co0 = blockIdx.y * CT;

  // tap offsets + validity, computed once
  int  off[K * K];
  bool valid[K * K];
  #pragma unroll
  for (int kh = 0; kh < K; kh++) {
    int hh = ho * stride + kh - pad;
    bool hv = (hh >= 0) & (hh < H);
    #pragma unroll
    for (int kw = 0; kw < K; kw++) {
      int ww = wo * stride + kw - pad;
      valid[kh * K + kw] = hv & (ww >= 0) & (ww < W);
      off[kh * K + kw]   = hh * W + ww;
    }
  }

  float acc[CT];
  #pragma unroll
  for (int c = 0; c < CT; c++) acc[c] = 0.f;

  const float* xb = x + (b * CIN) * H * W;
  for (int cb = 0; cb < CIN; cb += 4) {         // CIN % 4 == 0 always here
    float p[4][K * K];
    #pragma unroll
    for (int u = 0; u < 4; u++) {
      const float* xp = xb + (cb + u) * H * W;
      float m = 0.f, r = 0.f;
      if (INBN) { float2 t = smr[cb + u]; m = t.x; r = t.y; }
      #pragma unroll
      for (int t = 0; t < KK; t++) {
        float v = valid[t] ? xp[off[t]] : 0.f;
        if (INBN) v = valid[t] ? fmaxf((v - m) * r, 0.f) : 0.f;
        p[u][t] = v;
      }
    }
    #pragma unroll
    for (int c = 0; c < CT; c++) {
      const float* wp = w + ((co0 + c) * CIN + cb) * KK;   // wave-uniform
      #pragma unroll
      for (int u = 0; u < 4; u++)
        #pragma unroll
        for (int t = 0; t < KK; t++)
          acc[c] += fabsf(p[u][t] - wp[u * KK + t]);
    }
  }

  __shared__ float2 bred[4][CT];
  float2 mine[CT];
  #pragma unroll
  for (int c = 0; c < CT; c++) {
    float v = -acc[c];
    raw[(b * Cout + co0 + c) * HWo + hw] = v;
    float sx = v, sy = v * v;
    #pragma unroll
    for (int o2 = 32; o2; o2 >>= 1) {
      sx += __shfl_down(sx, o2, 64);
      sy += __shfl_down(sy, o2, 64);
    }
    mine[c] = make_float2(sx, sy);
  }
  int lane = threadIdx.x & 63, wid = threadIdx.x >> 6;
  if (lane == 0) {
    #pragma unroll
    for (int c = 0; c < CT; c++) bred[wid][c] = mine[c];
  }
  __syncthreads();
  if (threadIdx.x < CT) {
    float2 t = bred[0][threadIdx.x];
    #pragma unroll
    for (int wv = 1; wv < 4; wv++) { t.x += bred[wv][threadIdx.x].x; t.y += bred[wv][threadIdx.x].y; }
    partials[(co0 + threadIdx.x) * gridDim.x + blockIdx.x] = t;
  }
}

// ================================================================ conv stem + BN partials
// x [32,3,32,32], w [16,3,3,3], raw [32,16,32,32]. grid (128, 16), block 256.
__global__ void __launch_bounds__(256)
conv_stem_bn(const float* __restrict__ x, const float* __restrict__ w,
             float* __restrict__ raw, float2* __restrict__ partials) {
  const int co = blockIdx.y;
  const int i = blockIdx.x * 256 + threadIdx.x;   // over B*1024
  const int b = i >> 10, hw = i & 1023;
  const int ho = hw >> 5, wo = hw & 31;
  float acc = 0.f;
  #pragma unroll
  for (int ci = 0; ci < 3; ci++) {
    const float* xp = x + (b * 3 + ci) * 1024;
    #pragma unroll
    for (int kh = 0; kh < 3; kh++) {
      int hh = ho + kh - 1;
      bool hv = (hh >= 0) & (hh < 32);
      #pragma unroll
      for (int kw = 0; kw < 3; kw++) {
        int ww = wo + kw - 1;
        float xv = (hv & (ww >= 0) & (ww < 32)) ? xp[hh * 32 + ww] : 0.f;
        acc += xv * w[((co * 3 + ci) * 3 + kh) * 3 + kw];
      }
    }
  }
  raw[(b * 16 + co) * 1024 + hw] = acc;

  float sx = acc, sy = acc * acc;
  #pragma unroll
  for (int o2 = 32; o2; o2 >>= 1) {
    sx += __shfl_down(sx, o2, 64);
    sy += __shfl_down(sy, o2, 64);
  }
  __shared__ float2 red[4];
  int lane = threadIdx.x & 63, wid = threadIdx.x >> 6;
  if (lane == 0) red[wid] = make_float2(sx, sy);
  __syncthreads();
  if (threadIdx.x == 0) {
    float2 t = red[0];
    t.x += red[1].x + red[2].x + red[3].x;
    t.y += red[1].y + red[2].y + red[3].y;
    partials[co * 128 + blockIdx.x] = t;
  }
}

// ================================================================ combine
// h = relu( bn(raw2) + identity ); stats computed in-prologue from partials.
// IDMODE 0: identity = idsrc (materialized)
// IDMODE 1: identity = bn(idsrc)        (downsample raw)
// IDMODE 2: identity = relu(bn(idsrc))  (stem raw)
// POOL (HW must be 64, one wave per (b,c)): write pooled[b*C+c] instead of h.
template<int IDMODE, int C, bool POOL>
__global__ void __launch_bounds__(256)
combine_k(const float* __restrict__ raw2, const float2* __restrict__ part2, int nPart2,
          const float* __restrict__ idsrc, const float2* __restrict__ partI, int nPartI,
          float invN, float* __restrict__ out, int HW) {
  __shared__ float2 s2[C];
  __shared__ float2 sI[IDMODE ? C : 1];
  __shared__ float2 pred[256];
  stats_prologue<C>(part2, nPart2, invN, s2, pred);
  if (IDMODE) stats_prologue<C>(partI, nPartI, invN, sI, pred);

  int idx = blockIdx.x * 256 + threadIdx.x;
  int c = (idx / HW) % C;
  float2 t2 = s2[c];
  float y = (raw2[idx] - t2.x) * t2.y;
  float id;
  if (IDMODE == 0) id = idsrc[idx];
  else {
    float2 tI = sI[c];
    id = (idsrc[idx] - tI.x) * tI.y;
    if (IDMODE == 2) id = fmaxf(id, 0.f);
  }
  float h = fmaxf(y + id, 0.f);
  if (!POOL) {
    out[idx] = h;
  } else {
    float s = h;
    #pragma unroll
    for (int o2 = 32; o2; o2 >>= 1) s += __shfl_down(s, o2, 64);
    if ((threadIdx.x & 63) == 0) out[idx >> 6] = s * (1.f / 64.f);  // idx/64 = b*C+c
  }
}

// ================================================================ head
// pooled [32,64] -> fc (10,64) -> BN over batch -> out [32,10]
__global__ void head_k(const float* __restrict__ pooled, const float* __restrict__ fcw,
                       float* __restrict__ out) {
  __shared__ float logits[320];
  __shared__ float mn[10], rs[10];
  int t = threadIdx.x;
  if (t < 320) {
    int b = t / 10, o = t - b * 10;
    float s = 0.f;
    #pragma unroll
    for (int c = 0; c < 64; c++) s += pooled[b * 64 + c] * fcw[o * 64 + c];
    logits[t] = s;
  }
  __syncthreads();
  if (t < 10) {
    float s = 0.f;
    for (int b = 0; b < 32; b++) s += logits[b * 10 + t];
    float m = s * (1.f / 32.f);
    float v = 0.f;
    for (int b = 0; b < 32; b++) { float d = logits[b * 10 + t] - m; v += d * d; }
    mn[t] = m;
    rs[t] = rsqrtf(v * (1.f / 32.f) + BN_EPS);
  }
  __syncthreads();
  if (t < 320) out[t] = (logits[t] - mn[t % 10]) * rs[t % 10];
}

// ================================================================ host
extern "C" void kernel_launch(void* const* d_in, const int* in_sizes, int n_in,
                              void* d_out, int out_size, void* d_ws, size_t ws_size,
                              hipStream_t stream) {
  const float* x      = (const float*)d_in[0];
  const float* conv1w = (const float*)d_in[1];
  const float* l1w    = (const float*)d_in[2];
  const float* l2w0   = (const float*)d_in[3];
  const float* l2ws   = (const float*)d_in[4];
  const float* l2down = (const float*)d_in[5];
  const float* l3w0   = (const float*)d_in[6];
  const float* l3ws   = (const float*)d_in[7];
  const float* l3down = (const float*)d_in[8];
  const float* fcw    = (const float*)d_in[9];
  float* out = (float*)d_out;

  const int T2MB = 32 * 16 * 32 * 32;   // 524288 floats
  float* base = (float*)d_ws;
  float* R0 = base + 0 * T2MB;   // stem raw
  float* RA = base + 1 * T2MB;   // raw1
  float* RB = base + 2 * T2MB;   // raw2
  float* RD = base + 3 * T2MB;   // downsample raw
  float* H0 = base + 4 * T2MB;
  float* H1 = base + 5 * T2MB;
  float* pooled = base + 6 * T2MB;                  // 2048 floats
  float2* partS = (float2*)(pooled + 4096);
  float2* partA = partS + 4096;
  float2* partB = partA + 4096;
  float2* partD = partB + 4096;

  const float inv1 = 1.f / 32768.f;   // B*32*32
  const float inv2 = 1.f / 8192.f;    // B*16*16
  const float inv3 = 1.f / 2048.f;    // B*8*8

  // ---- stem
  conv_stem_bn<<<dim3(128, 16), 256, 0, stream>>>(x, conv1w, R0, partS);

  float* cur = H1;
  float* nxt = H0;

  // ======== layer1: 16ch @32x32, CT=2, grid (128,8)
  {
    const dim3 ag(128, 8);
    // block 0: input & identity come from stem raw (virtual relu(bn))
    adder_k<3, 2, 16, true ><<<ag, 256, 0, stream>>>(R0, partS, 128, inv1, l1w + 0 * 2304, RA, partA, 32, 16, 32, 32, 32, 32, 1, 1);
    adder_k<3, 2, 16, true ><<<ag, 256, 0, stream>>>(RA, partA, 128, inv1, l1w + 1 * 2304, RB, partB, 32, 16, 32, 32, 32, 32, 1, 1);
    combine_k<2, 16, false><<<2048, 256, 0, stream>>>(RB, partB, 128, R0, partS, 128, inv1, nxt, 1024);
    { float* t = cur; cur = nxt; nxt = t; }
    for (int i = 1; i < 3; i++) {
      adder_k<3, 2, 16, false><<<ag, 256, 0, stream>>>(cur, nullptr, 0, 0.f, l1w + (2 * i) * 2304, RA, partA, 32, 16, 32, 32, 32, 32, 1, 1);
      adder_k<3, 2, 16, true ><<<ag, 256, 0, stream>>>(RA, partA, 128, inv1, l1w + (2 * i + 1) * 2304, RB, partB, 32, 16, 32, 32, 32, 32, 1, 1);
      combine_k<0, 16, false><<<2048, 256, 0, stream>>>(RB, partB, 128, cur, nullptr, 0, inv1, nxt, 1024);
      float* t = cur; cur = nxt; nxt = t;
    }
  }

  // ======== layer2: 32ch @16x16, CT=2, grid (32,16)
  {
    const dim3 ag(32, 16);
    // block 0: stride 2, Cin=16, 1x1 downsample
    adder_k<3, 2, 16, false><<<ag, 256, 0, stream>>>(cur, nullptr, 0, 0.f, l2w0, RA, partA, 32, 32, 32, 32, 16, 16, 2, 1);
    adder_k<3, 2, 32, true ><<<ag, 256, 0, stream>>>(RA, partA, 32, inv2, l2ws + 0 * 9216, RB, partB, 32, 32, 16, 16, 16, 16, 1, 1);
    adder_k<1, 2, 16, false><<<ag, 256, 0, stream>>>(cur, nullptr, 0, 0.f, l2down, RD, partD, 32, 32, 32, 32, 16, 16, 2, 0);
    combine_k<1, 32, false><<<1024, 256, 0, stream>>>(RB, partB, 32, RD, partD, 32, inv2, nxt, 256);
    { float* t = cur; cur = nxt; nxt = t; }
    for (int i = 0; i < 2; i++) {
      adder_k<3, 2, 32, false><<<ag, 256, 0, stream>>>(cur, nullptr, 0, 0.f, l2ws + (1 + 2 * i) * 9216, RA, partA, 32, 32, 16, 16, 16, 16, 1, 1);
      adder_k<3, 2, 32, true ><<<ag, 256, 0, stream>>>(RA, partA, 32, inv2, l2ws + (2 + 2 * i) * 9216, RB, partB, 32, 32, 16, 16, 16, 16, 1, 1);
      combine_k<0, 32, false><<<1024, 256, 0, stream>>>(RB, partB, 32, cur, nullptr, 0, inv2, nxt, 256);
      float* t = cur; cur = nxt; nxt = t;
    }
  }

  // ======== layer3: 64ch @8x8, CT=1, grid (8,64)
  {
    const dim3 ag(8, 64);
    adder_k<3, 1, 32, false><<<ag, 256, 0, stream>>>(cur, nullptr, 0, 0.f, l3w0, RA, partA, 32, 64, 16, 16, 8, 8, 2, 1);
    adder_k<3, 1, 64, true ><<<ag, 256, 0, stream>>>(RA, partA, 8, inv3, l3ws + 0 * 36864, RB, partB, 32, 64, 8, 8, 8, 8, 1, 1);
    adder_k<1, 1, 32, false><<<ag, 256, 0, stream>>>(cur, nullptr, 0, 0.f, l3down, RD, partD, 32, 64, 16, 16, 8, 8, 2, 0);
    combine_k<1, 64, false><<<512, 256, 0, stream>>>(RB, partB, 8, RD, partD, 8, inv3, nxt, 64);
    { float* t = cur; cur = nxt; nxt = t; }
    // block 1
    adder_k<3, 1, 64, false><<<ag, 256, 0, stream>>>(cur, nullptr, 0, 0.f, l3ws + 1 * 36864, RA, partA, 32, 64, 8, 8, 8, 8, 1, 1);
    adder_k<3, 1, 64, true ><<<ag, 256, 0, stream>>>(RA, partA, 8, inv3, l3ws + 2 * 36864, RB, partB, 32, 64, 8, 8, 8, 8, 1, 1);
    combine_k<0, 64, false><<<512, 256, 0, stream>>>(RB, partB, 8, cur, nullptr, 0, inv3, nxt, 64);
    { float* t = cur; cur = nxt; nxt = t; }
    // block 2 (final): fuse global-avg-pool into combine
    adder_k<3, 1, 64, false><<<ag, 256, 0, stream>>>(cur, nullptr, 0, 0.f, l3ws + 3 * 36864, RA, partA, 32, 64, 8, 8, 8, 8, 1, 1);
    adder_k<3, 1, 64, true ><<<ag, 256, 0, stream>>>(RA, partA, 8, inv3, l3ws + 4 * 36864, RB, partB, 32, 64, 8, 8, 8, 8, 1, 1);
    combine_k<0, 64, true ><<<512, 256, 0, stream>>>(RB, partB, 8, cur, nullptr, 0, inv3, pooled, 64);
  }

  // ---- head
  head_k<<<1, 320, 0, stream>>>(pooled, fcw, out);
}

// Round 5
// 406.095 us; speedup vs baseline: 1.8750x; 1.0005x over previous
//
#include <hip/hip_runtime.h>

#define BN_EPS 1e-5f

// ================================================================ stats prologue
// Reduce per-block partials [C][nPart] -> smr[c] = (mean, rstd) in LDS.
// Fixed-order tree reduction: identical result in every block (deterministic).
template<int C>
__device__ __forceinline__ void stats_prologue(const float2* __restrict__ part,
                                               int nPart, float invN,
                                               float2* smr, float2* pred) {
  const int TPC = 256 / C;                 // threads per channel (4..16)
  int c  = threadIdx.x / TPC;
  int sl = threadIdx.x - c * TPC;
  float s = 0.f, s2 = 0.f;
  for (int j = sl; j < nPart; j += TPC) {
    float2 p = part[c * nPart + j];
    s += p.x; s2 += p.y;
  }
  pred[threadIdx.x] = make_float2(s, s2);
  __syncthreads();
  for (int st = TPC >> 1; st; st >>= 1) {
    if (sl < st) {
      pred[threadIdx.x].x += pred[threadIdx.x + st].x;
      pred[threadIdx.x].y += pred[threadIdx.x + st].y;
    }
    __syncthreads();
  }
  if (sl == 0) {
    float m   = pred[threadIdx.x].x * invN;
    float var = fmaxf(pred[threadIdx.x].y * invN - m * m, 0.f);
    smr[c] = make_float2(m, rsqrtf(var + BN_EPS));
  }
  __syncthreads();
}

// ================================================================ adder2d
// One thread = one output position (b,ho,wo) x CT output channels.
// blockDim 256 (4 waves). grid = (B*Ho*Wo/256, Cout/CT).
// CIB input channels batched per iteration: CIB*K*K independent loads in
// flight before any consume (latency hiding via ILP).
// INBN: input is raw pre-BN; relu((v-m)*r) applied to in-bounds loads only
// (zero padding stays 0: activation precedes patch extraction).
// DOWN: additionally compute the 1x1 stride-2 downsample adder on the SAME
// input using the center tap of the 3x3 patch (K==3, stride==2, pad==1 only),
// writing rawD/partialsD. Center tap (kh=1,kw=1) is always in-bounds.
template<int K, int CT, int CIB, int CIN, bool INBN, bool DOWN>
__global__ void __launch_bounds__(256, 2)
adder_k(const float* __restrict__ x, const float2* __restrict__ inpart,
        int nPartIn, float invNIn,
        const float* __restrict__ w, const float* __restrict__ wD,
        float* __restrict__ raw, float2* __restrict__ partials,
        float* __restrict__ rawD, float2* __restrict__ partialsD,
        int B, int Cout, int H, int W, int Ho, int Wo, int stride, int pad) {
  __shared__ float2 smr[INBN ? CIN : 1];
  __shared__ float2 pred[256];
  if (INBN) stats_prologue<CIN>(inpart, nPartIn, invNIn, smr, pred);

  const int KK  = K * K;
  const int HWo = Ho * Wo;
  const int i   = blockIdx.x * 256 + threadIdx.x;
  const int b   = i / HWo;
  const int hw  = i - b * HWo;
  const int ho  = hw / Wo, wo = hw - ho * Wo;
  const int co0 = blockIdx.y * CT;

  int  off[K * K];
  bool valid[K * K];
  #pragma unroll
  for (int kh = 0; kh < K; kh++) {
    int hh = ho * stride + kh - pad;
    bool hv = (hh >= 0) & (hh < H);
    #pragma unroll
    for (int kw = 0; kw < K; kw++) {
      int ww = wo * stride + kw - pad;
      valid[kh * K + kw] = hv & (ww >= 0) & (ww < W);
      off[kh * K + kw]   = hh * W + ww;
    }
  }

  float acc[CT];
  float accD[DOWN ? CT : 1];
  #pragma unroll
  for (int c = 0; c < CT; c++) acc[c] = 0.f;
  if (DOWN) {
    #pragma unroll
    for (int c = 0; c < CT; c++) accD[c] = 0.f;
  }

  const float* xb = x + (b * CIN) * H * W;
  for (int cb = 0; cb < CIN; cb += CIB) {
    float p[CIB][K * K];
    #pragma unroll
    for (int u = 0; u < CIB; u++) {
      const float* xp = xb + (cb + u) * H * W;
      float m = 0.f, r = 0.f;
      if (INBN) { float2 t = smr[cb + u]; m = t.x; r = t.y; }
      #pragma unroll
      for (int t = 0; t < KK; t++) {
        float v = valid[t] ? xp[off[t]] : 0.f;
        if (INBN) v = valid[t] ? fmaxf((v - m) * r, 0.f) : 0.f;
        p[u][t] = v;
      }
    }
    #pragma unroll
    for (int c = 0; c < CT; c++) {
      const float* wp = w + ((co0 + c) * CIN + cb) * KK;   // wave-uniform
      #pragma unroll
      for (int u = 0; u < CIB; u++)
        #pragma unroll
        for (int t = 0; t < KK; t++)
          acc[c] += fabsf(p[u][t] - wp[u * KK + t]);
    }
    if (DOWN) {
      #pragma unroll
      for (int c = 0; c < CT; c++) {
        const float* wdp = wD + (co0 + c) * CIN + cb;      // wave-uniform
        #pragma unroll
        for (int u = 0; u < CIB; u++)
          accD[c] += fabsf(p[u][(K * K) / 2] - wdp[u]);
      }
    }
  }

  __shared__ float2 bred[4][CT];
  int lane = threadIdx.x & 63, wid = threadIdx.x >> 6;

  // main output
  {
    float2 mine[CT];
    #pragma unroll
    for (int c = 0; c < CT; c++) {
      float v = -acc[c];
      raw[(b * Cout + co0 + c) * HWo + hw] = v;
      float sx = v, sy = v * v;
      #pragma unroll
      for (int o2 = 32; o2; o2 >>= 1) {
        sx += __shfl_down(sx, o2, 64);
        sy += __shfl_down(sy, o2, 64);
      }
      mine[c] = make_float2(sx, sy);
    }
    if (lane == 0) {
      #pragma unroll
      for (int c = 0; c < CT; c++) bred[wid][c] = mine[c];
    }
    __syncthreads();
    if (threadIdx.x < CT) {
      float2 t = bred[0][threadIdx.x];
      #pragma unroll
      for (int wv = 1; wv < 4; wv++) { t.x += bred[wv][threadIdx.x].x; t.y += bred[wv][threadIdx.x].y; }
      partials[(co0 + threadIdx.x) * gridDim.x + blockIdx.x] = t;
    }
  }
  // downsample output
  if (DOWN) {
    __syncthreads();
    float2 mine[CT];
    #pragma unroll
    for (int c = 0; c < CT; c++) {
      float v = -accD[c];
      rawD[(b * Cout + co0 + c) * HWo + hw] = v;
      float sx = v, sy = v * v;
      #pragma unroll
      for (int o2 = 32; o2; o2 >>= 1) {
        sx += __shfl_down(sx, o2, 64);
        sy += __shfl_down(sy, o2, 64);
      }
      mine[c] = make_float2(sx, sy);
    }
    if (lane == 0) {
      #pragma unroll
      for (int c = 0; c < CT; c++) bred[wid][c] = mine[c];
    }
    __syncthreads();
    if (threadIdx.x < CT) {
      float2 t = bred[0][threadIdx.x];
      #pragma unroll
      for (int wv = 1; wv < 4; wv++) { t.x += bred[wv][threadIdx.x].x; t.y += bred[wv][threadIdx.x].y; }
      partialsD[(co0 + threadIdx.x) * gridDim.x + blockIdx.x] = t;
    }
  }
}

// ================================================================ conv stem + BN partials
__global__ void __launch_bounds__(256)
conv_stem_bn(const float* __restrict__ x, const float* __restrict__ w,
             float* __restrict__ raw, float2* __restrict__ partials) {
  const int co = blockIdx.y;
  const int i = blockIdx.x * 256 + threadIdx.x;   // over B*1024
  const int b = i >> 10, hw = i & 1023;
  const int ho = hw >> 5, wo = hw & 31;
  float acc = 0.f;
  #pragma unroll
  for (int ci = 0; ci < 3; ci++) {
    const float* xp = x + (b * 3 + ci) * 1024;
    #pragma unroll
    for (int kh = 0; kh < 3; kh++) {
      int hh = ho + kh - 1;
      bool hv = (hh >= 0) & (hh < 32);
      #pragma unroll
      for (int kw = 0; kw < 3; kw++) {
        int ww = wo + kw - 1;
        float xv = (hv & (ww >= 0) & (ww < 32)) ? xp[hh * 32 + ww] : 0.f;
        acc += xv * w[((co * 3 + ci) * 3 + kh) * 3 + kw];
      }
    }
  }
  raw[(b * 16 + co) * 1024 + hw] = acc;

  float sx = acc, sy = acc * acc;
  #pragma unroll
  for (int o2 = 32; o2; o2 >>= 1) {
    sx += __shfl_down(sx, o2, 64);
    sy += __shfl_down(sy, o2, 64);
  }
  __shared__ float2 red[4];
  int lane = threadIdx.x & 63, wid = threadIdx.x >> 6;
  if (lane == 0) red[wid] = make_float2(sx, sy);
  __syncthreads();
  if (threadIdx.x == 0) {
    float2 t = red[0];
    t.x += red[1].x + red[2].x + red[3].x;
    t.y += red[1].y + red[2].y + red[3].y;
    partials[co * 128 + blockIdx.x] = t;
  }
}

// ================================================================ combine
// h = relu( bn(raw2) + identity ); stats from partials in prologue.
// IDMODE 0: identity = idsrc (materialized)
// IDMODE 1: identity = bn(idsrc)        (downsample raw)
// IDMODE 2: identity = relu(bn(idsrc))  (stem raw)
// POOL (HW==64): write pooled[b*C+c] (wave-reduced mean) instead of h.
template<int IDMODE, int C, bool POOL>
__global__ void __launch_bounds__(256)
combine_k(const float* __restrict__ raw2, const float2* __restrict__ part2, int nPart2,
          const float* __restrict__ idsrc, const float2* __restrict__ partI, int nPartI,
          float invN, float* __restrict__ out, int HW) {
  __shared__ float2 s2[C];
  __shared__ float2 sI[IDMODE ? C : 1];
  __shared__ float2 pred[256];
  stats_prologue<C>(part2, nPart2, invN, s2, pred);
  if (IDMODE) stats_prologue<C>(partI, nPartI, invN, sI, pred);

  int idx = blockIdx.x * 256 + threadIdx.x;
  int c = (idx / HW) % C;
  float2 t2 = s2[c];
  float y = (raw2[idx] - t2.x) * t2.y;
  float id;
  if (IDMODE == 0) id = idsrc[idx];
  else {
    float2 tI = sI[c];
    id = (idsrc[idx] - tI.x) * tI.y;
    if (IDMODE == 2) id = fmaxf(id, 0.f);
  }
  float h = fmaxf(y + id, 0.f);
  if (!POOL) {
    out[idx] = h;
  } else {
    float s = h;
    #pragma unroll
    for (int o2 = 32; o2; o2 >>= 1) s += __shfl_down(s, o2, 64);
    if ((threadIdx.x & 63) == 0) out[idx >> 6] = s * (1.f / 64.f);  // idx/64 = b*C+c
  }
}

// ================================================================ head
__global__ void head_k(const float* __restrict__ pooled, const float* __restrict__ fcw,
                       float* __restrict__ out) {
  __shared__ float logits[320];
  __shared__ float mn[10], rs[10];
  int t = threadIdx.x;
  if (t < 320) {
    int b = t / 10, o = t - b * 10;
    float s = 0.f;
    #pragma unroll
    for (int c = 0; c < 64; c++) s += pooled[b * 64 + c] * fcw[o * 64 + c];
    logits[t] = s;
  }
  __syncthreads();
  if (t < 10) {
    float s = 0.f;
    for (int b = 0; b < 32; b++) s += logits[b * 10 + t];
    float m = s * (1.f / 32.f);
    float v = 0.f;
    for (int b = 0; b < 32; b++) { float d = logits[b * 10 + t] - m; v += d * d; }
    mn[t] = m;
    rs[t] = rsqrtf(v * (1.f / 32.f) + BN_EPS);
  }
  __syncthreads();
  if (t < 320) out[t] = (logits[t] - mn[t % 10]) * rs[t % 10];
}

// ================================================================ host
extern "C" void kernel_launch(void* const* d_in, const int* in_sizes, int n_in,
                              void* d_out, int out_size, void* d_ws, size_t ws_size,
                              hipStream_t stream) {
  const float* x      = (const float*)d_in[0];
  const float* conv1w = (const float*)d_in[1];
  const float* l1w    = (const float*)d_in[2];
  const float* l2w0   = (const float*)d_in[3];
  const float* l2ws   = (const float*)d_in[4];
  const float* l2down = (const float*)d_in[5];
  const float* l3w0   = (const float*)d_in[6];
  const float* l3ws   = (const float*)d_in[7];
  const float* l3down = (const float*)d_in[8];
  const float* fcw    = (const float*)d_in[9];
  float* out = (float*)d_out;

  const int T2MB = 32 * 16 * 32 * 32;   // 524288 floats
  float* base = (float*)d_ws;
  float* R0 = base + 0 * T2MB;   // stem raw
  float* RA = base + 1 * T2MB;   // raw1
  float* RB = base + 2 * T2MB;   // raw2
  float* RD = base + 3 * T2MB;   // downsample raw
  float* H0 = base + 4 * T2MB;
  float* H1 = base + 5 * T2MB;
  float* pooled = base + 6 * T2MB;                  // 2048 floats
  float2* partS = (float2*)(pooled + 4096);
  float2* partA = partS + 4096;
  float2* partB = partA + 4096;
  float2* partD = partB + 4096;

  const float inv1 = 1.f / 32768.f;   // B*32*32
  const float inv2 = 1.f / 8192.f;    // B*16*16
  const float inv3 = 1.f / 2048.f;    // B*8*8

  conv_stem_bn<<<dim3(128, 16), 256, 0, stream>>>(x, conv1w, R0, partS);

  float* cur = H1;
  float* nxt = H0;

  // ======== layer1: 16ch @32x32, CT=2, CIB=4, grid (128,8)
  {
    const dim3 ag(128, 8);
    adder_k<3, 2, 4, 16, true , false><<<ag, 256, 0, stream>>>(R0, partS, 128, inv1, l1w + 0 * 2304, nullptr, RA, partA, nullptr, nullptr, 32, 16, 32, 32, 32, 32, 1, 1);
    adder_k<3, 2, 4, 16, true , false><<<ag, 256, 0, stream>>>(RA, partA, 128, inv1, l1w + 1 * 2304, nullptr, RB, partB, nullptr, nullptr, 32, 16, 32, 32, 32, 32, 1, 1);
    combine_k<2, 16, false><<<2048, 256, 0, stream>>>(RB, partB, 128, R0, partS, 128, inv1, nxt, 1024);
    { float* t = cur; cur = nxt; nxt = t; }
    for (int i = 1; i < 3; i++) {
      adder_k<3, 2, 4, 16, false, false><<<ag, 256, 0, stream>>>(cur, nullptr, 0, 0.f, l1w + (2 * i) * 2304, nullptr, RA, partA, nullptr, nullptr, 32, 16, 32, 32, 32, 32, 1, 1);
      adder_k<3, 2, 4, 16, true , false><<<ag, 256, 0, stream>>>(RA, partA, 128, inv1, l1w + (2 * i + 1) * 2304, nullptr, RB, partB, nullptr, nullptr, 32, 16, 32, 32, 32, 32, 1, 1);
      combine_k<0, 16, false><<<2048, 256, 0, stream>>>(RB, partB, 128, cur, nullptr, 0, inv1, nxt, 1024);
      float* t = cur; cur = nxt; nxt = t;
    }
  }

  // ======== layer2: 32ch @16x16, CT=2, CIB=8, grid (32,16)
  {
    const dim3 ag(32, 16);
    // block 0: stride 2, Cin=16 (CIB=8), fused 1x1 downsample
    adder_k<3, 2, 8, 16, false, true ><<<ag, 256, 0, stream>>>(cur, nullptr, 0, 0.f, l2w0, l2down, RA, partA, RD, partD, 32, 32, 32, 32, 16, 16, 2, 1);
    adder_k<3, 2, 8, 32, true , false><<<ag, 256, 0, stream>>>(RA, partA, 32, inv2, l2ws + 0 * 9216, nullptr, RB, partB, nullptr, nullptr, 32, 32, 16, 16, 16, 16, 1, 1);
    combine_k<1, 32, false><<<1024, 256, 0, stream>>>(RB, partB, 32, RD, partD, 32, inv2, nxt, 256);
    { float* t = cur; cur = nxt; nxt = t; }
    for (int i = 0; i < 2; i++) {
      adder_k<3, 2, 8, 32, false, false><<<ag, 256, 0, stream>>>(cur, nullptr, 0, 0.f, l2ws + (1 + 2 * i) * 9216, nullptr, RA, partA, nullptr, nullptr, 32, 32, 16, 16, 16, 16, 1, 1);
      adder_k<3, 2, 8, 32, true , false><<<ag, 256, 0, stream>>>(RA, partA, 32, inv2, l2ws + (2 + 2 * i) * 9216, nullptr, RB, partB, nullptr, nullptr, 32, 32, 16, 16, 16, 16, 1, 1);
      combine_k<0, 32, false><<<1024, 256, 0, stream>>>(RB, partB, 32, cur, nullptr, 0, inv2, nxt, 256);
      float* t = cur; cur = nxt; nxt = t;
    }
  }

  // ======== layer3: 64ch @8x8, CT=1, CIB=8, grid (8,64)
  {
    const dim3 ag(8, 64);
    adder_k<3, 1, 8, 32, false, true ><<<ag, 256, 0, stream>>>(cur, nullptr, 0, 0.f, l3w0, l3down, RA, partA, RD, partD, 32, 64, 16, 16, 8, 8, 2, 1);
    adder_k<3, 1, 8, 64, true , false><<<ag, 256, 0, stream>>>(RA, partA, 8, inv3, l3ws + 0 * 36864, nullptr, RB, partB, nullptr, nullptr, 32, 64, 8, 8, 8, 8, 1, 1);
    combine_k<1, 64, false><<<512, 256, 0, stream>>>(RB, partB, 8, RD, partD, 8, inv3, nxt, 64);
    { float* t = cur; cur = nxt; nxt = t; }
    // block 1
    adder_k<3, 1, 8, 64, false, false><<<ag, 256, 0, stream>>>(cur, nullptr, 0, 0.f, l3ws + 1 * 36864, nullptr, RA, partA, nullptr, nullptr, 32, 64, 8, 8, 8, 8, 1, 1);
    adder_k<3, 1, 8, 64, true , false><<<ag, 256, 0, stream>>>(RA, partA, 8, inv3, l3ws + 2 * 36864, nullptr, RB, partB, nullptr, nullptr, 32, 64, 8, 8, 8, 8, 1, 1);
    combine_k<0, 64, false><<<512, 256, 0, stream>>>(RB, partB, 8, cur, nullptr, 0, inv3, nxt, 64);
    { float* t = cur; cur = nxt; nxt = t; }
    // block 2 (final): fuse global-avg-pool into combine
    adder_k<3, 1, 8, 64, false, false><<<ag, 256, 0, stream>>>(cur, nullptr, 0, 0.f, l3ws + 3 * 36864, nullptr, RA, partA, nullptr, nullptr, 32, 64, 8, 8, 8, 8, 1, 1);
    adder_k<3, 1, 8, 64, true , false><<<ag, 256, 0, stream>>>(RA, partA, 8, inv3, l3ws + 4 * 36864, nullptr, RB, partB, nullptr, nullptr, 32, 64, 8, 8, 8, 8, 1, 1);
    combine_k<0, 64, true ><<<512, 256, 0, stream>>>(RB, partB, 8, cur, nullptr, 0, inv3, pooled, 64);
  }

  head_k<<<1, 320, 0, stream>>>(pooled, fcw, out);
}

// Round 6
// 370.089 us; speedup vs baseline: 2.0574x; 1.0973x over previous
//
#include <hip/hip_runtime.h>

#define BN_EPS 1e-5f

// ================================================================ stats prologue
// Reduce per-block/wave partials [C][nPart] -> smr[c]=(mean,rstd) in LDS.
// Fixed-order tree: identical result in every block (deterministic).
template<int C>
__device__ __forceinline__ void stats_prologue(const float2* __restrict__ part,
                                               int nPart, float invN,
                                               float2* smr, float2* pred) {
  const int TPC = 256 / C;
  int c  = threadIdx.x / TPC;
  int sl = threadIdx.x - c * TPC;
  float s = 0.f, s2 = 0.f;
  for (int j = sl; j < nPart; j += TPC) {
    float2 p = part[c * nPart + j];
    s += p.x; s2 += p.y;
  }
  pred[threadIdx.x] = make_float2(s, s2);
  __syncthreads();
  for (int st = TPC >> 1; st; st >>= 1) {
    if (sl < st) {
      pred[threadIdx.x].x += pred[threadIdx.x + st].x;
      pred[threadIdx.x].y += pred[threadIdx.x + st].y;
    }
    __syncthreads();
  }
  if (sl == 0) {
    float m   = pred[threadIdx.x].x * invN;
    float var = fmaxf(pred[threadIdx.x].y * invN - m * m, 0.f);
    smr[c] = make_float2(m, rsqrtf(var + BN_EPS));
  }
  __syncthreads();
}

// ================================================================ adder stage-1 (split-K)
// grid = (B*Ho*Wo/256, Cout/4, Cin/8). Each thread: one position, 4 output
// channels, 8 input channels (72 loads in flight, 288 |a-b| accumulates).
// Writes POSITIVE partial sums: pout[z*plane + (b*Cout+co)*HWo + hw].
// INBN: input is raw pre-BN; relu((v-m)*r) on in-bounds loads only (zero
// padding stays 0: activation precedes patch extraction).
// DOWN: also 1x1 stride-2 downsample adder via the (always valid) center tap.
template<int CIN, bool INBN, bool DOWN>
__global__ void __launch_bounds__(256, 4)
adder_s1(const float* __restrict__ x, const float2* __restrict__ inpart,
         int nPartIn, float invNIn,
         const float* __restrict__ w, const float* __restrict__ wD,
         float* __restrict__ pout, float* __restrict__ poutD,
         int B, int Cout, int H, int W, int Ho, int Wo,
         int stride, int pad, int plane) {
  __shared__ float2 smr[INBN ? CIN : 1];
  __shared__ float2 pred[INBN ? 256 : 1];
  if (INBN) stats_prologue<CIN>(inpart, nPartIn, invNIn, smr, pred);

  const int HWo = Ho * Wo;
  const int i   = blockIdx.x * 256 + threadIdx.x;
  const int b   = i / HWo;
  const int hw  = i - b * HWo;
  const int ho  = hw / Wo, wo = hw - ho * Wo;
  const int co0 = blockIdx.y * 4;
  const int ci0 = blockIdx.z * 8;

  int  off[9];
  bool valid[9];
  #pragma unroll
  for (int kh = 0; kh < 3; kh++) {
    int hh = ho * stride + kh - pad;
    bool hv = (hh >= 0) & (hh < H);
    #pragma unroll
    for (int kw = 0; kw < 3; kw++) {
      int ww = wo * stride + kw - pad;
      valid[kh * 3 + kw] = hv & (ww >= 0) & (ww < W);
      off[kh * 3 + kw]   = hh * W + ww;
    }
  }

  float p[8][9];
  #pragma unroll
  for (int u = 0; u < 8; u++) {
    const float* xp = x + (b * CIN + ci0 + u) * H * W;
    float m = 0.f, r = 0.f;
    if (INBN) { float2 t = smr[ci0 + u]; m = t.x; r = t.y; }
    #pragma unroll
    for (int t = 0; t < 9; t++) {
      float v = valid[t] ? xp[off[t]] : 0.f;
      if (INBN) v = valid[t] ? fmaxf((v - m) * r, 0.f) : 0.f;
      p[u][t] = v;
    }
  }

  float acc[4];
  float accD[DOWN ? 4 : 1];
  #pragma unroll
  for (int c = 0; c < 4; c++) acc[c] = 0.f;
  if (DOWN) {
    #pragma unroll
    for (int c = 0; c < 4; c++) accD[c] = 0.f;
  }

  #pragma unroll
  for (int c = 0; c < 4; c++) {
    const float* wp = w + ((co0 + c) * CIN + ci0) * 9;   // wave-uniform -> s_load
    #pragma unroll
    for (int u = 0; u < 8; u++)
      #pragma unroll
      for (int t = 0; t < 9; t++)
        acc[c] += fabsf(p[u][t] - wp[u * 9 + t]);
    if (DOWN) {
      const float* wdp = wD + (co0 + c) * CIN + ci0;
      #pragma unroll
      for (int u = 0; u < 8; u++)
        accD[c] += fabsf(p[u][4] - wdp[u]);
    }
  }

  const int zb = blockIdx.z * plane;
  #pragma unroll
  for (int c = 0; c < 4; c++) {
    pout[zb + (b * Cout + co0 + c) * HWo + hw] = acc[c];
    if (DOWN) poutD[zb + (b * Cout + co0 + c) * HWo + hw] = accD[c];
  }
}

// ================================================================ stage-2 reduce
// raw[e] = -sum_z pin[z*plane+e]; emit BN partials.
// BR: per-block partial (requires HWo>=256); else per-wave (HWo==64).
// DUAL: also finalize the downsample stream.
template<int NC, bool DUAL, bool BR>
__global__ void __launch_bounds__(256)
reduce_k(const float* __restrict__ pin, float* __restrict__ raw, float2* __restrict__ parts,
         const float* __restrict__ pinD, float* __restrict__ rawD, float2* __restrict__ partsD,
         int Cout, int HWo, int plane, int nPart) {
  const int e = blockIdx.x * 256 + threadIdx.x;
  const int b  = e / (Cout * HWo);
  const int r  = e - b * Cout * HWo;
  const int co = r / HWo;
  const int hw = r - co * HWo;
  const int lane = threadIdx.x & 63, wid = threadIdx.x >> 6;
  __shared__ float2 bb[4];

  {
    float s = 0.f;
    #pragma unroll
    for (int z = 0; z < NC; z++) s += pin[z * plane + e];
    float v = -s;
    raw[e] = v;
    float sx = v, sy = v * v;
    #pragma unroll
    for (int o2 = 32; o2; o2 >>= 1) {
      sx += __shfl_down(sx, o2, 64);
      sy += __shfl_down(sy, o2, 64);
    }
    if (BR) {
      if (lane == 0) bb[wid] = make_float2(sx, sy);
      __syncthreads();
      if (threadIdx.x == 0) {
        float2 t = bb[0];
        t.x += bb[1].x + bb[2].x + bb[3].x;
        t.y += bb[1].y + bb[2].y + bb[3].y;
        parts[co * nPart + ((b * HWo + hw) >> 8)] = t;
      }
    } else {
      if (lane == 0) parts[co * nPart + ((b * HWo + hw) >> 6)] = make_float2(sx, sy);
    }
  }

  if (DUAL) {
    if (BR) __syncthreads();
    float s = 0.f;
    #pragma unroll
    for (int z = 0; z < NC; z++) s += pinD[z * plane + e];
    float v = -s;
    rawD[e] = v;
    float sx = v, sy = v * v;
    #pragma unroll
    for (int o2 = 32; o2; o2 >>= 1) {
      sx += __shfl_down(sx, o2, 64);
      sy += __shfl_down(sy, o2, 64);
    }
    if (BR) {
      if (lane == 0) bb[wid] = make_float2(sx, sy);
      __syncthreads();
      if (threadIdx.x == 0) {
        float2 t = bb[0];
        t.x += bb[1].x + bb[2].x + bb[3].x;
        t.y += bb[1].y + bb[2].y + bb[3].y;
        partsD[co * nPart + ((b * HWo + hw) >> 8)] = t;
      }
    } else {
      if (lane == 0) partsD[co * nPart + ((b * HWo + hw) >> 6)] = make_float2(sx, sy);
    }
  }
}

// ================================================================ conv stem + BN partials
__global__ void __launch_bounds__(256)
conv_stem_bn(const float* __restrict__ x, const float* __restrict__ w,
             float* __restrict__ raw, float2* __restrict__ partials) {
  const int co = blockIdx.y;
  const int i = blockIdx.x * 256 + threadIdx.x;   // over B*1024
  const int b = i >> 10, hw = i & 1023;
  const int ho = hw >> 5, wo = hw & 31;
  float acc = 0.f;
  #pragma unroll
  for (int ci = 0; ci < 3; ci++) {
    const float* xp = x + (b * 3 + ci) * 1024;
    #pragma unroll
    for (int kh = 0; kh < 3; kh++) {
      int hh = ho + kh - 1;
      bool hv = (hh >= 0) & (hh < 32);
      #pragma unroll
      for (int kw = 0; kw < 3; kw++) {
        int ww = wo + kw - 1;
        float xv = (hv & (ww >= 0) & (ww < 32)) ? xp[hh * 32 + ww] : 0.f;
        acc += xv * w[((co * 3 + ci) * 3 + kh) * 3 + kw];
      }
    }
  }
  raw[(b * 16 + co) * 1024 + hw] = acc;

  float sx = acc, sy = acc * acc;
  #pragma unroll
  for (int o2 = 32; o2; o2 >>= 1) {
    sx += __shfl_down(sx, o2, 64);
    sy += __shfl_down(sy, o2, 64);
  }
  __shared__ float2 red[4];
  int lane = threadIdx.x & 63, wid = threadIdx.x >> 6;
  if (lane == 0) red[wid] = make_float2(sx, sy);
  __syncthreads();
  if (threadIdx.x == 0) {
    float2 t = red[0];
    t.x += red[1].x + red[2].x + red[3].x;
    t.y += red[1].y + red[2].y + red[3].y;
    partials[co * 128 + blockIdx.x] = t;
  }
}

// ================================================================ combine
// h = relu( bn(raw2) + identity ); stats from partials in prologue.
// IDMODE 0: identity = idsrc (materialized)
// IDMODE 1: identity = bn(idsrc)        (downsample raw)
// IDMODE 2: identity = relu(bn(idsrc))  (stem raw)
// POOL (HW==64): write pooled[b*C+c] (wave-reduced mean) instead of h.
template<int IDMODE, int C, bool POOL>
__global__ void __launch_bounds__(256)
combine_k(const float* __restrict__ raw2, const float2* __restrict__ part2, int nPart2,
          const float* __restrict__ idsrc, const float2* __restrict__ partI, int nPartI,
          float invN, float* __restrict__ out, int HW) {
  __shared__ float2 s2[C];
  __shared__ float2 sI[IDMODE ? C : 1];
  __shared__ float2 pred[256];
  stats_prologue<C>(part2, nPart2, invN, s2, pred);
  if (IDMODE) stats_prologue<C>(partI, nPartI, invN, sI, pred);

  int idx = blockIdx.x * 256 + threadIdx.x;
  int c = (idx / HW) % C;
  float2 t2 = s2[c];
  float y = (raw2[idx] - t2.x) * t2.y;
  float id;
  if (IDMODE == 0) id = idsrc[idx];
  else {
    float2 tI = sI[c];
    id = (idsrc[idx] - tI.x) * tI.y;
    if (IDMODE == 2) id = fmaxf(id, 0.f);
  }
  float h = fmaxf(y + id, 0.f);
  if (!POOL) {
    out[idx] = h;
  } else {
    float s = h;
    #pragma unroll
    for (int o2 = 32; o2; o2 >>= 1) s += __shfl_down(s, o2, 64);
    if ((threadIdx.x & 63) == 0) out[idx >> 6] = s * (1.f / 64.f);  // idx/64 = b*C+c
  }
}

// ================================================================ head
__global__ void head_k(const float* __restrict__ pooled, const float* __restrict__ fcw,
                       float* __restrict__ out) {
  __shared__ float logits[320];
  __shared__ float mn[10], rs[10];
  int t = threadIdx.x;
  if (t < 320) {
    int b = t / 10, o = t - b * 10;
    float s = 0.f;
    #pragma unroll
    for (int c = 0; c < 64; c++) s += pooled[b * 64 + c] * fcw[o * 64 + c];
    logits[t] = s;
  }
  __syncthreads();
  if (t < 10) {
    float s = 0.f;
    for (int b = 0; b < 32; b++) s += logits[b * 10 + t];
    float m = s * (1.f / 32.f);
    float v = 0.f;
    for (int b = 0; b < 32; b++) { float d = logits[b * 10 + t] - m; v += d * d; }
    mn[t] = m;
    rs[t] = rsqrtf(v * (1.f / 32.f) + BN_EPS);
  }
  __syncthreads();
  if (t < 320) out[t] = (logits[t] - mn[t % 10]) * rs[t % 10];
}

// ================================================================ host
extern "C" void kernel_launch(void* const* d_in, const int* in_sizes, int n_in,
                              void* d_out, int out_size, void* d_ws, size_t ws_size,
                              hipStream_t stream) {
  const float* x      = (const float*)d_in[0];
  const float* conv1w = (const float*)d_in[1];
  const float* l1w    = (const float*)d_in[2];
  const float* l2w0   = (const float*)d_in[3];
  const float* l2ws   = (const float*)d_in[4];
  const float* l2down = (const float*)d_in[5];
  const float* l3w0   = (const float*)d_in[6];
  const float* l3ws   = (const float*)d_in[7];
  const float* l3down = (const float*)d_in[8];
  const float* fcw    = (const float*)d_in[9];
  float* out = (float*)d_out;

  const int T2MB = 32 * 16 * 32 * 32;   // 524288 floats = 2 MB
  float* base = (float*)d_ws;
  float* R0 = base + 0 * T2MB;          // stem raw
  float* RA = base + 1 * T2MB;          // raw1
  float* RB = base + 2 * T2MB;          // raw2
  float* RD = base + 3 * T2MB;          // downsample raw
  float* H0 = base + 4 * T2MB;
  float* H1 = base + 5 * T2MB;
  float* PA = base + 6 * T2MB;          // split partials main (<= 4 MB)
  float* PD = base + 8 * T2MB;          // split partials down (<= 2 MB)
  float* sm = base + 9 * T2MB;
  float* pooled = sm;                   // 2048 floats
  float2* partS = (float2*)(sm + 4096);
  float2* partA = partS + 4096;
  float2* partB = partA + 4096;
  float2* partD = partB + 4096;

  const int B = 32;
  const float inv1 = 1.f / 32768.f;     // B*32*32
  const float inv2 = 1.f / 8192.f;      // B*16*16
  const float inv3 = 1.f / 2048.f;      // B*8*8

  // plane sizes (B*Cout*HWo)
  const int pl1 = 32 * 16 * 1024;       // 524288
  const int pl2 = 32 * 32 * 256;        // 262144
  const int pl3 = 32 * 64 * 64;         // 131072

  conv_stem_bn<<<dim3(128, 16), 256, 0, stream>>>(x, conv1w, R0, partS);

  float* cur = H1;
  float* nxt = H0;

  // ======== layer1: 16ch @32x32. s1 grid (128,4,2); reduce grid 2048; nPart 128
  {
    const dim3 ag(128, 4, 2);
    for (int i = 0; i < 3; i++) {
      const float* w1 = l1w + (2 * i) * 2304;
      const float* w2 = l1w + (2 * i + 1) * 2304;
      if (i == 0)
        adder_s1<16, true , false><<<ag, 256, 0, stream>>>(R0, partS, 128, inv1, w1, nullptr, PA, nullptr, B, 16, 32, 32, 32, 32, 1, 1, pl1);
      else
        adder_s1<16, false, false><<<ag, 256, 0, stream>>>(cur, nullptr, 0, 0.f, w1, nullptr, PA, nullptr, B, 16, 32, 32, 32, 32, 1, 1, pl1);
      reduce_k<2, false, true><<<2048, 256, 0, stream>>>(PA, RA, partA, nullptr, nullptr, nullptr, 16, 1024, pl1, 128);
      adder_s1<16, true , false><<<ag, 256, 0, stream>>>(RA, partA, 128, inv1, w2, nullptr, PA, nullptr, B, 16, 32, 32, 32, 32, 1, 1, pl1);
      reduce_k<2, false, true><<<2048, 256, 0, stream>>>(PA, RB, partB, nullptr, nullptr, nullptr, 16, 1024, pl1, 128);
      if (i == 0)
        combine_k<2, 16, false><<<2048, 256, 0, stream>>>(RB, partB, 128, R0, partS, 128, inv1, nxt, 1024);
      else
        combine_k<0, 16, false><<<2048, 256, 0, stream>>>(RB, partB, 128, cur, nullptr, 0, inv1, nxt, 1024);
      float* t = cur; cur = nxt; nxt = t;
    }
  }

  // ======== layer2: 32ch @16x16. nPart 32
  {
    // block 0: stride 2, Cin=16, fused 1x1 downsample. s1 grid (32,8,2)
    adder_s1<16, false, true ><<<dim3(32, 8, 2), 256, 0, stream>>>(cur, nullptr, 0, 0.f, l2w0, l2down, PA, PD, B, 32, 32, 32, 16, 16, 2, 1, pl2);
    reduce_k<2, true , true><<<1024, 256, 0, stream>>>(PA, RA, partA, PD, RD, partD, 32, 256, pl2, 32);
    adder_s1<32, true , false><<<dim3(32, 8, 4), 256, 0, stream>>>(RA, partA, 32, inv2, l2ws + 0 * 9216, nullptr, PA, nullptr, B, 32, 16, 16, 16, 16, 1, 1, pl2);
    reduce_k<4, false, true><<<1024, 256, 0, stream>>>(PA, RB, partB, nullptr, nullptr, nullptr, 32, 256, pl2, 32);
    combine_k<1, 32, false><<<1024, 256, 0, stream>>>(RB, partB, 32, RD, partD, 32, inv2, nxt, 256);
    { float* t = cur; cur = nxt; nxt = t; }
    for (int i = 0; i < 2; i++) {
      adder_s1<32, false, false><<<dim3(32, 8, 4), 256, 0, stream>>>(cur, nullptr, 0, 0.f, l2ws + (1 + 2 * i) * 9216, nullptr, PA, nullptr, B, 32, 16, 16, 16, 16, 1, 1, pl2);
      reduce_k<4, false, true><<<1024, 256, 0, stream>>>(PA, RA, partA, nullptr, nullptr, nullptr, 32, 256, pl2, 32);
      adder_s1<32, true , false><<<dim3(32, 8, 4), 256, 0, stream>>>(RA, partA, 32, inv2, l2ws + (2 + 2 * i) * 9216, nullptr, PA, nullptr, B, 32, 16, 16, 16, 16, 1, 1, pl2);
      reduce_k<4, false, true><<<1024, 256, 0, stream>>>(PA, RB, partB, nullptr, nullptr, nullptr, 32, 256, pl2, 32);
      combine_k<0, 32, false><<<1024, 256, 0, stream>>>(RB, partB, 32, cur, nullptr, 0, inv2, nxt, 256);
      float* t = cur; cur = nxt; nxt = t;
    }
  }

  // ======== layer3: 64ch @8x8. nPart 32 (per-wave, HWo=64)
  {
    // block 0: stride 2, Cin=32, fused 1x1 downsample. s1 grid (8,16,4)
    adder_s1<32, false, true ><<<dim3(8, 16, 4), 256, 0, stream>>>(cur, nullptr, 0, 0.f, l3w0, l3down, PA, PD, B, 64, 16, 16, 8, 8, 2, 1, pl3);
    reduce_k<4, true , false><<<512, 256, 0, stream>>>(PA, RA, partA, PD, RD, partD, 64, 64, pl3, 32);
    adder_s1<64, true , false><<<dim3(8, 16, 8), 256, 0, stream>>>(RA, partA, 32, inv3, l3ws + 0 * 36864, nullptr, PA, nullptr, B, 64, 8, 8, 8, 8, 1, 1, pl3);
    reduce_k<8, false, false><<<512, 256, 0, stream>>>(PA, RB, partB, nullptr, nullptr, nullptr, 64, 64, pl3, 32);
    combine_k<1, 64, false><<<512, 256, 0, stream>>>(RB, partB, 32, RD, partD, 32, inv3, nxt, 64);
    { float* t = cur; cur = nxt; nxt = t; }
    for (int i = 0; i < 2; i++) {
      adder_s1<64, false, false><<<dim3(8, 16, 8), 256, 0, stream>>>(cur, nullptr, 0, 0.f, l3ws + (1 + 2 * i) * 36864, nullptr, PA, nullptr, B, 64, 8, 8, 8, 8, 1, 1, pl3);
      reduce_k<8, false, false><<<512, 256, 0, stream>>>(PA, RA, partA, nullptr, nullptr, nullptr, 64, 64, pl3, 32);
      adder_s1<64, true , false><<<dim3(8, 16, 8), 256, 0, stream>>>(RA, partA, 32, inv3, l3ws + (2 + 2 * i) * 36864, nullptr, PA, nullptr, B, 64, 8, 8, 8, 8, 1, 1, pl3);
      reduce_k<8, false, false><<<512, 256, 0, stream>>>(PA, RB, partB, nullptr, nullptr, nullptr, 64, 64, pl3, 32);
      if (i == 1)
        combine_k<0, 64, true ><<<512, 256, 0, stream>>>(RB, partB, 32, cur, nullptr, 0, inv3, pooled, 64);
      else
        combine_k<0, 64, false><<<512, 256, 0, stream>>>(RB, partB, 32, cur, nullptr, 0, inv3, nxt, 64);
      if (i == 0) { float* t = cur; cur = nxt; nxt = t; }
    }
  }

  head_k<<<1, 320, 0, stream>>>(pooled, fcw, out);
}